// Round 3
// baseline (516.264 us; speedup 1.0000x reference)
//
#include <hip/hip_runtime.h>
#include <math.h>

#define N_ 16
#define C_ 3
#define H_ 512
#define W_ 512
#define HW_ (H_ * W_)
#define PLANE_ (N_ * HW_)   // 4194304 pixels
#define R_ 4
#define TILE 32
#define REG 40              // TILE + 2*R_
#define GAMMA_ 2.0f

__device__ __forceinline__ float wave_reduce(float v) {
#pragma unroll
    for (int off = 32; off > 0; off >>= 1)
        v += __shfl_down(v, off, 64);
    return v;
}

// MODE 0: store wr/diff planes + accumulate sum(wr) into scalars[0]
// MODE 1: accumulate sum(wr) only (no stores; low-ws fallback)
// MODE 2: recompute wr/diff, accumulate sum(w) -> scalars[1], sum(w*diff) -> scalars[2]
template <int MODE>
__global__ __launch_bounds__(256) void tile_kernel(const float* __restrict__ x,
                                                   float* __restrict__ wr_plane,
                                                   float* __restrict__ diff_plane,
                                                   float* __restrict__ scalars) {
    __shared__ float fld[6][REG][REG];    // 38400 B
    __shared__ float hsum[6][REG][TILE];  // 30720 B

    const int tid = threadIdx.x;
    const int tx = blockIdx.x * TILE;
    const int ty = blockIdx.y * TILE;
    const int b = blockIdx.z;
    const float* xb = x + (size_t)b * (C_ * HW_);

    // Load 40x40 halo region, compute the 6 derived fields.
    for (int pos = tid; pos < REG * REG; pos += 256) {
        int r = pos / REG, c = pos - r * REG;
        int gy = (ty + r - R_) & (H_ - 1);
        int gx = (tx + c - R_) & (W_ - 1);
        int idx = gy * W_ + gx;
        float x0 = xb[idx];
        float x1 = xb[HW_ + idx];
        float x2 = xb[2 * HW_ + idx];
        float y = (x0 + x1 + x2) * (1.0f / 3.0f);
        float d = x0 - x2;
        fld[0][r][c] = x0;
        fld[1][r][c] = x1;
        fld[2][r][c] = x2;
        fld[3][r][c] = x0 * x0 + x1 * x1 + x2 * x2;
        fld[4][r][c] = y * y;
        fld[5][r][c] = d * d;
    }
    __syncthreads();

    // Horizontal 9-sum: 40 rows x 32 cols.
    for (int pos = tid; pos < REG * TILE; pos += 256) {
        int r = pos / TILE, c = pos - r * TILE;
#pragma unroll
        for (int f = 0; f < 6; ++f) {
            float s = 0.0f;
#pragma unroll
            for (int k = 0; k < 9; ++k) s += fld[f][r][c + k];
            hsum[f][r][c] = s;
        }
    }
    __syncthreads();

    float coef = 0.0f;
    if (MODE == 2) coef = GAMMA_ * (float)HW_ / scalars[0];

    const float inv81 = 1.0f / 81.0f;
    float acc0 = 0.0f, acc1 = 0.0f;

    // Vertical 9-sum + epilogue: 32x32 outputs.
    for (int pos = tid; pos < TILE * TILE; pos += 256) {
        int r = pos / TILE, c = pos - r * TILE;
        float vs[6];
#pragma unroll
        for (int f = 0; f < 6; ++f) {
            float s = 0.0f;
#pragma unroll
            for (int k = 0; k < 9; ++k) s += hsum[f][r + k][c];
            vs[f] = s * inv81;
        }
        float B0 = vs[0], B1 = vs[1], B2 = vs[2];
        float alpha = (vs[3] - (B0 * B0 + B1 * B1 + B2 * B2)) * (1.0f / 3.0f);
        float my = (B0 + B1 + B2) * (1.0f / 3.0f);
        float beta = vs[4] - my * my;
        float md = B0 - B2;
        float wr = (2.0f / 3.0f) * (vs[5] - md * md);
        float diff = alpha - beta;

        if (MODE == 0) {
            int gidx = b * HW_ + (ty + r) * W_ + (tx + c);
            wr_plane[gidx] = wr;
            diff_plane[gidx] = diff;
            acc0 += wr;
        } else if (MODE == 1) {
            acc0 += wr;
        } else {
            float w = expf(-coef * wr);
            acc0 += w;
            acc1 += w * diff;
        }
    }

    if (MODE <= 1) {
        float s = wave_reduce(acc0);
        if ((tid & 63) == 0) atomicAdd(&scalars[0], s);
    } else {
        float s0 = wave_reduce(acc0);
        float s1 = wave_reduce(acc1);
        if ((tid & 63) == 0) {
            atomicAdd(&scalars[1], s0);
            atomicAdd(&scalars[2], s1);
        }
    }
}

// Pass 2 (store path): elementwise exp + reductions over the two planes.
__global__ __launch_bounds__(256) void weight_kernel(const float* __restrict__ wr_plane,
                                                     const float* __restrict__ diff_plane,
                                                     float* __restrict__ scalars) {
    const float coef = GAMMA_ * (float)HW_ / scalars[0];
    const float4* wr4 = (const float4*)wr_plane;
    const float4* df4 = (const float4*)diff_plane;
    const int n4 = PLANE_ / 4;
    float sw = 0.0f, swd = 0.0f;
    int stride = gridDim.x * blockDim.x;
    for (int i = blockIdx.x * blockDim.x + threadIdx.x; i < n4; i += stride) {
        float4 a = wr4[i];
        float4 d = df4[i];
        float w0 = expf(-coef * a.x);
        float w1 = expf(-coef * a.y);
        float w2 = expf(-coef * a.z);
        float w3 = expf(-coef * a.w);
        sw += (w0 + w1) + (w2 + w3);
        swd += (w0 * d.x + w1 * d.y) + (w2 * d.z + w3 * d.w);
    }
    sw = wave_reduce(sw);
    swd = wave_reduce(swd);
    if ((threadIdx.x & 63) == 0) {
        atomicAdd(&scalars[1], sw);
        atomicAdd(&scalars[2], swd);
    }
}

__global__ void final_kernel(const float* __restrict__ scalars, float* __restrict__ out) {
    out[0] = 1.5f * scalars[2] / scalars[1];
}

extern "C" void kernel_launch(void* const* d_in, const int* in_sizes, int n_in,
                              void* d_out, int out_size, void* d_ws, size_t ws_size,
                              hipStream_t stream) {
    const float* x = (const float*)d_in[0];
    float* out = (float*)d_out;
    float* scalars = (float*)d_ws;  // scalars[0]=sum(wr), [1]=sum(w), [2]=sum(w*diff)

    // zero the accumulators (ws is poisoned to 0xAA before every call)
    hipMemsetAsync(d_ws, 0, 16, stream);

    dim3 grid(W_ / TILE, H_ / TILE, N_);
    const size_t need = 256 + 2 * (size_t)PLANE_ * sizeof(float);

    if (ws_size >= need) {
        float* wr_plane = (float*)((char*)d_ws + 256);
        float* diff_plane = wr_plane + PLANE_;
        tile_kernel<0><<<grid, 256, 0, stream>>>(x, wr_plane, diff_plane, scalars);
        weight_kernel<<<2048, 256, 0, stream>>>(wr_plane, diff_plane, scalars);
    } else {
        tile_kernel<1><<<grid, 256, 0, stream>>>(x, nullptr, nullptr, scalars);
        tile_kernel<2><<<grid, 256, 0, stream>>>(x, nullptr, nullptr, scalars);
    }
    final_kernel<<<1, 1, 0, stream>>>(scalars, out);
}

// Round 6
// 136.528 us; speedup vs baseline: 3.7814x; 3.7814x over previous
//
#include <hip/hip_runtime.h>
#include <math.h>

#define N_ 16
#define C_ 3
#define H_ 512
#define W_ 512
#define HW_ (H_ * W_)
#define PLANE_ (N_ * HW_)   // 4194304 pixels
#define BAND 8              // output rows per block
#define GAMMA_ 2.0f

__device__ __forceinline__ float wave_reduce(float v) {
#pragma unroll
    for (int off = 32; off > 0; off >>= 1)
        v += __shfl_down(v, off, 64);
    return v;
}

// MODE 0: store wr/diff planes + sum(wr) -> scalars[0]
// MODE 1: sum(wr) only (no stores; low-ws fallback)
// MODE 2: recompute, w = exp(-coef*wr); sum(w) -> scalars[1], sum(w*diff) -> scalars[2]
template <int MODE>
__global__ __launch_bounds__(256) void pass1(const float* __restrict__ x,
                                             float* __restrict__ wr_plane,
                                             float* __restrict__ diff_plane,
                                             float* __restrict__ scalars) {
    __shared__ float rowbuf[6][W_];   // 12288 B: vertically-summed row, 6 fields
    __shared__ float red[8];

    const int tid = threadIdx.x;
    const int c0 = tid * 2;           // this thread owns cols c0, c0+1
    const int y0 = blockIdx.x * BAND;
    const int b = blockIdx.y;
    const float* xb = x + (size_t)b * (C_ * HW_);

    float coef = 0.0f;
    if (MODE == 2) coef = GAMMA_ * (float)HW_ / scalars[0];

    // running vertical 9-row sums of the 6 derived fields, 2 cols each
    float vs[6][2];
#pragma unroll
    for (int f = 0; f < 6; ++f) vs[f][0] = vs[f][1] = 0.0f;

    auto row_update = [&](int r, float sgn) {
        int rr = r & (H_ - 1);
        const float* p = xb + rr * W_ + c0;
        float2 a0 = *(const float2*)(p);
        float2 a1 = *(const float2*)(p + HW_);
        float2 a2 = *(const float2*)(p + 2 * HW_);
#pragma unroll
        for (int i = 0; i < 2; ++i) {
            float x0 = i ? a0.y : a0.x;
            float x1 = i ? a1.y : a1.x;
            float x2 = i ? a2.y : a2.x;
            float yv = (x0 + x1 + x2) * (1.0f / 3.0f);
            float d = x0 - x2;
            vs[0][i] = fmaf(sgn, x0, vs[0][i]);
            vs[1][i] = fmaf(sgn, x1, vs[1][i]);
            vs[2][i] = fmaf(sgn, x2, vs[2][i]);
            vs[3][i] = fmaf(sgn, x0 * x0 + x1 * x1 + x2 * x2, vs[3][i]);
            vs[4][i] = fmaf(sgn, yv * yv, vs[4][i]);
            vs[5][i] = fmaf(sgn, d * d, vs[5][i]);
        }
    };

    // init: window rows y0-4 .. y0+4
#pragma unroll
    for (int k = 0; k < 9; ++k) row_update(y0 - 4 + k, 1.0f);

    float accwr = 0.0f, accw = 0.0f, accwd = 0.0f;
    const float inv81 = 1.0f / 81.0f;

    for (int y = y0; y < y0 + BAND; ++y) {
        // publish vertically-summed row
#pragma unroll
        for (int f = 0; f < 6; ++f)
            *(float2*)&rowbuf[f][c0] = make_float2(vs[f][0], vs[f][1]);
        __syncthreads();

        // horizontal 9-sum for cols c0, c0+1 (sliding share of 8 taps)
        float hs[6][2];
#pragma unroll
        for (int f = 0; f < 6; ++f) {
            float2 v[5];
#pragma unroll
            for (int j = 0; j < 5; ++j)
                v[j] = *(const float2*)&rowbuf[f][(c0 + 2 * j - 4) & (W_ - 1)];
            float s0 = ((v[0].x + v[0].y) + (v[1].x + v[1].y)) +
                       ((v[2].x + v[2].y) + (v[3].x + v[3].y)) + v[4].x;
            float s1 = s0 - v[0].x + v[4].y;
            hs[f][0] = s0;
            hs[f][1] = s1;
        }

        float wrv[2], dfv[2];
#pragma unroll
        for (int i = 0; i < 2; ++i) {
            float B0 = hs[0][i] * inv81, B1 = hs[1][i] * inv81, B2 = hs[2][i] * inv81;
            float alpha = (hs[3][i] * inv81 - (B0 * B0 + B1 * B1 + B2 * B2)) * (1.0f / 3.0f);
            float my = (B0 + B1 + B2) * (1.0f / 3.0f);
            float beta = hs[4][i] * inv81 - my * my;
            float md = B0 - B2;
            float wr = (2.0f / 3.0f) * (hs[5][i] * inv81 - md * md);
            float df = alpha - beta;
            wrv[i] = wr;
            dfv[i] = df;
            if (MODE <= 1) {
                accwr += wr;
            } else {
                float w = __expf(-coef * wr);
                accw += w;
                accwd += w * df;
            }
        }
        if (MODE == 0) {
            int gidx = b * HW_ + y * W_ + c0;
            *(float2*)&wr_plane[gidx] = make_float2(wrv[0], wrv[1]);
            *(float2*)&diff_plane[gidx] = make_float2(dfv[0], dfv[1]);
        }
        __syncthreads();  // rowbuf consumed; safe to overwrite next iter

        // slide window: add row y+5, drop row y-4
        if (y + 1 < y0 + BAND) {
            row_update(y + 5, 1.0f);
            row_update(y - 4, -1.0f);
        }
    }

    // block-level reduction -> 1 atomic per scalar per block
    if (MODE <= 1) {
        float s = wave_reduce(accwr);
        if ((tid & 63) == 0) red[tid >> 6] = s;
        __syncthreads();
        if (tid == 0) atomicAdd(&scalars[0], (red[0] + red[1]) + (red[2] + red[3]));
    } else {
        float s0 = wave_reduce(accw);
        float s1 = wave_reduce(accwd);
        if ((tid & 63) == 0) {
            red[tid >> 6] = s0;
            red[4 + (tid >> 6)] = s1;
        }
        __syncthreads();
        if (tid == 0) {
            atomicAdd(&scalars[1], (red[0] + red[1]) + (red[2] + red[3]));
            atomicAdd(&scalars[2], (red[4] + red[5]) + (red[6] + red[7]));
        }
    }
}

// Pass 2 (store path): exp + global reductions over the two planes.
__global__ __launch_bounds__(256) void weight_kernel(const float* __restrict__ wr_plane,
                                                     const float* __restrict__ diff_plane,
                                                     float* __restrict__ scalars) {
    __shared__ float red[8];
    const float coef = GAMMA_ * (float)HW_ / scalars[0];
    const float4* wr4 = (const float4*)wr_plane;
    const float4* df4 = (const float4*)diff_plane;
    const int n4 = PLANE_ / 4;
    float sw = 0.0f, swd = 0.0f;
    int stride = gridDim.x * blockDim.x;
    for (int i = blockIdx.x * blockDim.x + threadIdx.x; i < n4; i += stride) {
        float4 a = wr4[i];
        float4 d = df4[i];
        float w0 = __expf(-coef * a.x);
        float w1 = __expf(-coef * a.y);
        float w2 = __expf(-coef * a.z);
        float w3 = __expf(-coef * a.w);
        sw += (w0 + w1) + (w2 + w3);
        swd += (w0 * d.x + w1 * d.y) + (w2 * d.z + w3 * d.w);
    }
    sw = wave_reduce(sw);
    swd = wave_reduce(swd);
    int tid = threadIdx.x;
    if ((tid & 63) == 0) {
        red[tid >> 6] = sw;
        red[4 + (tid >> 6)] = swd;
    }
    __syncthreads();
    if (tid == 0) {
        atomicAdd(&scalars[1], (red[0] + red[1]) + (red[2] + red[3]));
        atomicAdd(&scalars[2], (red[4] + red[5]) + (red[6] + red[7]));
    }
}

__global__ void final_kernel(const float* __restrict__ scalars, float* __restrict__ out) {
    out[0] = 1.5f * scalars[2] / scalars[1];
}

extern "C" void kernel_launch(void* const* d_in, const int* in_sizes, int n_in,
                              void* d_out, int out_size, void* d_ws, size_t ws_size,
                              hipStream_t stream) {
    const float* x = (const float*)d_in[0];
    float* out = (float*)d_out;
    float* scalars = (float*)d_ws;  // [0]=sum(wr), [1]=sum(w), [2]=sum(w*diff)

    hipMemsetAsync(d_ws, 0, 16, stream);

    dim3 grid(H_ / BAND, N_);  // 64 x 16 = 1024 blocks
    const size_t need = 256 + 2 * (size_t)PLANE_ * sizeof(float);

    if (ws_size >= need) {
        float* wr_plane = (float*)((char*)d_ws + 256);
        float* diff_plane = wr_plane + PLANE_;
        pass1<0><<<grid, 256, 0, stream>>>(x, wr_plane, diff_plane, scalars);
        weight_kernel<<<1024, 256, 0, stream>>>(wr_plane, diff_plane, scalars);
    } else {
        pass1<1><<<grid, 256, 0, stream>>>(x, nullptr, nullptr, scalars);
        pass1<2><<<grid, 256, 0, stream>>>(x, nullptr, nullptr, scalars);
    }
    final_kernel<<<1, 1, 0, stream>>>(scalars, out);
}